// Round 6
// baseline (294.005 us; speedup 1.0000x reference)
//
#include <hip/hip_runtime.h>
#include <hip/hip_bf16.h>

// Inputs (f32): fm [64][768][676], att_w [192][768], att_b [192],
//               fc_w [200][24576], fc_b [200]
// d_out (f32): p [64*200] | fm_n [64*32*768] | att_m [64*32*676]
// ws: fmb16 bf16 [64][768][704] | {att_pad bf16 [64][32][704] UNION
//     p_part f32 [48][64][208]} | pooled f32 [64][32][768] |
//     fmn16 bf16 [64*24576] | p_sums f32 [64]
// R6: k_cvt fused into k_att (fm f32 read once, coalesced 256B/row staging,
// bf16 written to LDS for frags AND to fmb16 for k_pool). Per-wave p-ownership
// -> register-direct epilogue, 12 barriers total.

typedef unsigned short u16;
typedef __bf16 bf16x8_t __attribute__((ext_vector_type(8)));
typedef float f32x4_t __attribute__((ext_vector_type(4)));
typedef unsigned int uint32x4 __attribute__((ext_vector_type(4)));
typedef unsigned int uint32x2 __attribute__((ext_vector_type(2)));

union Frag { uint32x4 u4; unsigned u[4]; u16 s[8]; bf16x8_t v; };
union BFU { __hip_bfloat16 h; u16 u; };

__device__ inline u16 f2b(float x) { BFU t; t.h = __float2bfloat16(x); return t.u; }

__device__ inline void load8_cvt(const float* p, Frag& f) {
    f32x4_t x0 = *(const f32x4_t*)(p);
    f32x4_t x1 = *(const f32x4_t*)(p + 4);
#pragma unroll
    for (int j = 0; j < 4; ++j) { f.s[j] = f2b(x0[j]); f.s[4 + j] = f2b(x1[j]); }
}

#define MFMA(a, b, c) __builtin_amdgcn_mfma_f32_16x16x32_bf16((a), (b), (c), 0, 0, 0)

// ---- Pass 1 (fused cvt+att): att = relu(att_w[:32] @ fm[b] + att_b); emits fmb16 ----
// grid (11, 64). Tile 32m x 64p; wave wv owns p-cols [wv*16, +16) for ALL K.
// K-chunks of 128: stage f32 coalesced -> bf16 -> LDS [128][66] + fmb16.
__global__ __launch_bounds__(256) void k_att(
    const float* __restrict__ fm, const float* __restrict__ att_w,
    const float* __restrict__ att_b, float* __restrict__ att_out,
    __hip_bfloat16* __restrict__ att_pad, u16* __restrict__ fmb16,
    float* __restrict__ p_sums)
{
    const int b  = blockIdx.y;
    const int p0 = blockIdx.x << 6;          // 0..640
    const int t  = threadIdx.x;
    const int wv = t >> 6, l = t & 63, q = l >> 4, ln = l & 15;

    if (blockIdx.x == 0 && b == 0 && t < 64) p_sums[t] = 0.f;  // k_pool atomics

    __shared__ u16 tile[128 * 66];           // 16.9 KB, stride 66 breaks conflicts

    f32x4_t acc[2] = {{0.f,0.f,0.f,0.f},{0.f,0.f,0.f,0.f}};

    const int  sr   = t >> 3;                // staging row 0..31 (+32*s)
    const int  sc8  = (t & 7) << 3;          // staging col 0,8,..,56
    const bool edge = (p0 + sc8 + 7) >= 676; // only in last p-tile

    for (int k0 = 0; k0 < 768; k0 += 128) {
        if (k0) __syncthreads();             // protect prev chunk's frag reads
#pragma unroll
        for (int s = 0; s < 4; ++s) {
            const int r = sr + 32 * s;       // 0..127
            const float* src = fm + (size_t)(b * 768 + k0 + r) * 676 + p0 + sc8;
            Frag val;
            if (!edge) {
                load8_cvt(src, val);
            } else {                         // guarded scalar loads; pad = true zero
#pragma unroll
                for (int i = 0; i < 8; ++i)
                    val.s[i] = (p0 + sc8 + i < 676) ? f2b(src[i]) : (u16)0;
            }
            unsigned* dst = (unsigned*)&tile[r * 66 + sc8];
            dst[0]=val.u[0]; dst[1]=val.u[1]; dst[2]=val.u[2]; dst[3]=val.u[3];
            *(uint32x4*)(fmb16 + (size_t)(b * 768 + k0 + r) * 704 + p0 + sc8) = val.u4;
        }
        __syncthreads();

#pragma unroll
        for (int ks = 0; ks < 4; ++ks) {
            const int kk = k0 + ks * 32;
            Frag a0, a1, bfr;
            load8_cvt(att_w + (size_t)ln * 768 + kk + q * 8, a0);          // m 0..15
            load8_cvt(att_w + (size_t)(16 + ln) * 768 + kk + q * 8, a1);   // m 16..31
            const int rb = ks * 32 + q * 8;
#pragma unroll
            for (int j = 0; j < 8; ++j)
                bfr.s[j] = tile[(rb + j) * 66 + wv * 16 + ln];
            acc[0] = MFMA(a0.v, bfr.v, acc[0]);
            acc[1] = MFMA(a1.v, bfr.v, acc[1]);
        }
    }

    // register-direct epilogue: lane holds D[m = mh*16+q*4+r][p = p0+wv*16+ln]
    const int  p   = p0 + wv * 16 + ln;
    const bool pok = p < 676;
#pragma unroll
    for (int mh = 0; mh < 2; ++mh) {
#pragma unroll
        for (int r = 0; r < 4; ++r) {
            const int m = mh * 16 + q * 4 + r;
            float x = acc[mh][r] + att_b[m];
            x = x > 0.f ? x : 0.f;
            ((u16*)att_pad)[(size_t)(b * 32 + m) * 704 + p] = pok ? f2b(x) : (u16)0;
            if (pok) att_out[(size_t)(b * 32 + m) * 676 + p] = x;
        }
    }
}

// ---------------- Pass 2: pooled[b] = att[b](32x704) @ fm[b]^T / 676 ----------------
// grid (24, 64). Tile 32m x 32c. 22 k-steps striped across 4 waves; no barriers
// in loop. All-bf16 dwordx4 loads; pads are zero on both operands.
__global__ __launch_bounds__(256) void k_pool(
    const u16* __restrict__ fmb16, const u16* __restrict__ att_pad,
    float* __restrict__ pooled, float* __restrict__ p_sums)
{
    const int b  = blockIdx.y;
    const int n0 = blockIdx.x << 5;
    const int t  = threadIdx.x;
    const int wv = t >> 6, l = t & 63, q = l >> 4, ln = l & 15;

    __shared__ float red[32][32][4];
    __shared__ float rs[4];

    const u16* Ab = att_pad + (size_t)b * 32 * 704;
    const u16* B0 = fmb16 + (size_t)(b * 768 + n0 + ln) * 704;
    const u16* B1 = fmb16 + (size_t)(b * 768 + n0 + 16 + ln) * 704;

    f32x4_t acc[2][2] = {{{0.f,0.f,0.f,0.f},{0.f,0.f,0.f,0.f}},
                         {{0.f,0.f,0.f,0.f},{0.f,0.f,0.f,0.f}}};

    for (int it = wv; it < 22; it += 4) {
        const int k = it * 32 + q * 8;
        Frag a0, a1, b0, b1;
        a0.u4 = *(const uint32x4*)(Ab + (size_t)ln * 704 + k);
        a1.u4 = *(const uint32x4*)(Ab + (size_t)(16 + ln) * 704 + k);
        b0.u4 = *(const uint32x4*)(B0 + k);
        b1.u4 = *(const uint32x4*)(B1 + k);
        acc[0][0] = MFMA(a0.v, b0.v, acc[0][0]);
        acc[0][1] = MFMA(a0.v, b1.v, acc[0][1]);
        acc[1][0] = MFMA(a1.v, b0.v, acc[1][0]);
        acc[1][1] = MFMA(a1.v, b1.v, acc[1][1]);
    }

#pragma unroll
    for (int mh = 0; mh < 2; ++mh)
#pragma unroll
        for (int ch = 0; ch < 2; ++ch)
#pragma unroll
            for (int r = 0; r < 4; ++r)
                red[mh * 16 + q * 4 + r][ch * 16 + ln][wv] = acc[mh][ch][r];
    __syncthreads();

    const float sc = 1.0f / 676.0f;
    const int m = t >> 3, c0 = (t & 7) << 2;
    float ls = 0.f;
#pragma unroll
    for (int j = 0; j < 4; ++j) {
        const int cl = c0 + j;
        f32x4_t v4 = *(const f32x4_t*)&red[m][cl][0];
        float v = (v4[0] + v4[1] + v4[2] + v4[3]) * sc;
        pooled[(size_t)(b * 32 + m) * 768 + n0 + cl] = v;
        ls += fabsf(v);
    }
    for (int off = 32; off > 0; off >>= 1) ls += __shfl_down(ls, off);
    if (l == 0) rs[wv] = ls;
    __syncthreads();
    if (t == 0) atomicAdd(p_sums + b, rs[0] + rs[1] + rs[2] + rs[3]);
}

// ---------------- Pass 3 (apply only): signed sqrt + L2 normalize ----------------
__global__ __launch_bounds__(256) void k_norm(
    const float* __restrict__ pooled, const float* __restrict__ p_sums,
    float* __restrict__ fm_out, u16* __restrict__ fmn16)
{
    const int b = blockIdx.x;
    const size_t base = (size_t)b * 24576 + (size_t)blockIdx.y * 2048;
    const float tot = p_sums[b] + 24576.f * 1e-12f;
    const float inv = 1.f / fmaxf(sqrtf(tot), 1e-12f);
    const int t = threadIdx.x;
#pragma unroll
    for (int i = 0; i < 8; ++i) {
        const size_t idx = base + i * 256 + t;
        float x = pooled[idx];
        float v = (x == 0.f) ? 0.f : copysignf(sqrtf(fabsf(x) + 1e-12f), x);
        float o = v * inv;
        fm_out[idx] = o;
        fmn16[idx]  = f2b(o);
    }
}

// ---------------- Pass 4: p partials, K=24576 split into 48 slabs of 512 ----------------
__global__ __launch_bounds__(256) void k_fc(
    const u16* __restrict__ fmn16, const float* __restrict__ fc_w,
    float* __restrict__ p_part)
{
    const int ntile = blockIdx.x;          // 0..12
    const int slab  = blockIdx.y;          // 0..47
    const int t = threadIdx.x;
    const int wv = t >> 6, l = t & 63, q = l >> 4, ln = l & 15;
    const int n = ntile * 16 + ln;
    const int kbase = slab * 512;

    const u16*   Ab = fmn16 + (size_t)(wv * 16 + ln) * 24576 + kbase + q * 8;
    const float* Bb = fc_w + (size_t)n * 24576 + kbase + q * 8;
    const bool nok = n < 200;

    f32x4_t acc = {0.f, 0.f, 0.f, 0.f};
#pragma unroll
    for (int kk = 0; kk < 512; kk += 32) {
        Frag af, bf2;
        af.u4 = *(const uint32x4*)(Ab + kk);
        if (nok) load8_cvt(Bb + kk, bf2);
        else { bf2.u[0] = 0u; bf2.u[1] = 0u; bf2.u[2] = 0u; bf2.u[3] = 0u; }
        acc = MFMA(af.v, bf2.v, acc);
    }
#pragma unroll
    for (int r = 0; r < 4; ++r) {
        const int bb = wv * 16 + q * 4 + r;
        p_part[(size_t)(slab * 64 + bb) * 208 + ntile * 16 + ln] = acc[r];
    }
}

// ---------------- Pass 5: reduce 48 slabs, scale 100, + bias ----------------
__global__ __launch_bounds__(256) void k_fin(
    const float* __restrict__ p_part, const float* __restrict__ fc_b,
    float* __restrict__ p_out)
{
    const int tid = blockIdx.x * 256 + threadIdx.x;   // 50*256 == 12800
    const int b = tid / 200, n = tid - b * 200;
    float s = 0.f;
#pragma unroll
    for (int sl = 0; sl < 48; ++sl) s += p_part[(size_t)(sl * 64 + b) * 208 + n];
    p_out[tid] = s * 100.f + fc_b[n];
}

extern "C" void kernel_launch(void* const* d_in, const int* in_sizes, int n_in,
                              void* d_out, int out_size, void* d_ws, size_t ws_size,
                              hipStream_t stream)
{
    const float* fm    = (const float*)d_in[0];
    const float* att_w = (const float*)d_in[1];
    const float* att_b = (const float*)d_in[2];
    const float* fc_w  = (const float*)d_in[3];
    const float* fc_b  = (const float*)d_in[4];

    float* out     = (float*)d_out;
    float* p_out   = out;                         // [64][200]
    float* fm_out  = out + 12800;                 // [64][32][768]
    float* att_out = out + 12800 + 64 * 32 * 768; // [64][32][676]

    char* ws = (char*)d_ws;
    u16* fmb16 = (u16*)ws;                                   // 69,206,016 B
    __hip_bfloat16* att_pad = (__hip_bfloat16*)(ws + 69206016);  // 2,883,584 B (UNION p_part)
    float* p_part = (float*)(ws + 69206016);
    float* pooled = (float*)(ws + 69206016 + 2883584);       // 6,291,456 B
    u16*   fmn16  = (u16*)(ws + 69206016 + 2883584 + 6291456); // 3,145,728 B
    float* p_sums = (float*)(ws + 69206016 + 2883584 + 6291456 + 3145728); // 256 B

    k_att <<<dim3(11, 64), 256, 0, stream>>>(fm, att_w, att_b, att_out, att_pad, fmb16, p_sums);
    k_pool<<<dim3(24, 64), 256, 0, stream>>>(fmb16, (const u16*)att_pad, pooled, p_sums);
    k_norm<<<dim3(64, 12), 256, 0, stream>>>(pooled, p_sums, fm_out, fmn16);
    k_fc  <<<dim3(13, 48), 256, 0, stream>>>(fmn16, fc_w, p_part);
    k_fin <<<dim3(50),     256, 0, stream>>>(p_part, fc_b, p_out);
}

// Round 7
// 260.213 us; speedup vs baseline: 1.1299x; 1.1299x over previous
//
#include <hip/hip_runtime.h>
#include <hip/hip_bf16.h>

// Inputs (f32): fm [64][768][676], att_w [192][768], att_b [192],
//               fc_w [200][24576], fc_b [200]
// d_out (f32): p [64*200] | fm_n [64*32*768] | att_m [64*32*676]
// ws: {att_pad bf16 [64][32][704] UNION p_part f32 [48][64][208]} |
//     pooled f32 [64][32][768] | fmn16 bf16 [64*24576] | p_sums f32 [64]
// R7: no bf16 mirror of fm. k_att reads f32 fm once via a register-held
// prefetch pipeline (loads for chunk c+1 in flight during chunk c's MFMAs),
// double-buffered bf16 LDS tiles, one barrier per 128-K chunk. k_pool re-reads
// f32 fm (L3-resident, 133 MB < 256 MB L3) with inline cvt.

typedef unsigned short u16;
typedef __bf16 bf16x8_t __attribute__((ext_vector_type(8)));
typedef float f32x4_t __attribute__((ext_vector_type(4)));
typedef unsigned int uint32x4 __attribute__((ext_vector_type(4)));
typedef unsigned int uint32x2 __attribute__((ext_vector_type(2)));

union Frag { uint32x4 u4; unsigned u[4]; u16 s[8]; bf16x8_t v; };
union BFU { __hip_bfloat16 h; u16 u; };

__device__ inline u16 f2b(float x) { BFU t; t.h = __float2bfloat16(x); return t.u; }

__device__ inline void load8_cvt(const float* p, Frag& f) {
    f32x4_t x0 = *(const f32x4_t*)(p);
    f32x4_t x1 = *(const f32x4_t*)(p + 4);
#pragma unroll
    for (int j = 0; j < 4; ++j) { f.s[j] = f2b(x0[j]); f.s[4 + j] = f2b(x1[j]); }
}

#define MFMA(a, b, c) __builtin_amdgcn_mfma_f32_16x16x32_bf16((a), (b), (c), 0, 0, 0)

// ---- Pass 1: att = relu(att_w[:32] @ fm[b] + att_b) ----
// grid (11, 64). Tile 32m x 64p. K in 6 chunks of 128; wave wv computes the
// ks=wv K=32 slice of each chunk (partials reduced via LDS at the end).
// Pipeline per chunk: issue next chunk's float4 loads -> MFMA current ->
// cvt+ds_write next -> barrier. LDS: 2 x [128][66] bf16, aliased by reduce.
__global__ __launch_bounds__(256) void k_att(
    const float* __restrict__ fm, const float* __restrict__ att_w,
    const float* __restrict__ att_b, float* __restrict__ att_out,
    u16* __restrict__ att_pad, float* __restrict__ p_sums)
{
    const int b  = blockIdx.y;
    const int p0 = blockIdx.x << 6;          // 0..640
    const int t  = threadIdx.x;
    const int wv = t >> 6, l = t & 63, q = l >> 4, ln = l & 15;

    if (blockIdx.x == 0 && b == 0 && t < 64) p_sums[t] = 0.f;  // k_pool atomics

    __shared__ u16 smem[2 * 8448];           // 2 bufs of [128][66] bf16 = 33 KB
    float* red = (float*)smem;               // aliased [32][64][4] after pipeline

    const int  rr  = t >> 4;                 // base staging row 0..15
    const int  c4  = t & 15;                 // float4 col slot (fixed per thread)
    const bool cok = (p0 + c4 * 4 + 3) < 676;    // edge only at p0==640 (c4>=9)
    const float* fbase = fm + (size_t)(b * 768) * 676 + p0 + c4 * 4;

    f32x4_t pre[8];
    f32x4_t acc[2][4];
#pragma unroll
    for (int i = 0; i < 2; ++i)
#pragma unroll
        for (int j = 0; j < 4; ++j) acc[i][j] = f32x4_t{0.f, 0.f, 0.f, 0.f};

    auto loadf = [&](int c) {                // 8 independent float4 loads in flight
#pragma unroll
        for (int i = 0; i < 8; ++i) {
            const int r = rr + 16 * i;       // rows 0..127 of chunk
            pre[i] = cok ? *(const f32x4_t*)(fbase + (size_t)(c * 128 + r) * 676)
                         : f32x4_t{0.f, 0.f, 0.f, 0.f};
        }
    };
    auto commit = [&](int buf) {             // cvt + LDS write (needs loads done)
        u16* tp = smem + buf * 8448;
#pragma unroll
        for (int i = 0; i < 8; ++i) {
            const int r = rr + 16 * i;
            uint32x2 w;
            w[0] = (unsigned)f2b(pre[i][0]) | ((unsigned)f2b(pre[i][1]) << 16);
            w[1] = (unsigned)f2b(pre[i][2]) | ((unsigned)f2b(pre[i][3]) << 16);
            *(uint32x2*)(tp + r * 66 + c4 * 4) = w;
        }
    };
    auto compute = [&](int c, int buf) {
        const u16* tp = smem + buf * 8448;
        const int kk = c * 128 + wv * 32;
        Frag a0, a1, bf[4];
        load8_cvt(att_w + (size_t)ln * 768 + kk + q * 8, a0);          // m 0..15
        load8_cvt(att_w + (size_t)(16 + ln) * 768 + kk + q * 8, a1);   // m 16..31
        const u16* bp = tp + (wv * 32 + q * 8) * 66 + ln;
#pragma unroll
        for (int pc = 0; pc < 4; ++pc)
#pragma unroll
            for (int j = 0; j < 8; ++j)
                bf[pc].s[j] = bp[j * 66 + pc * 16];
#pragma unroll
        for (int pc = 0; pc < 4; ++pc) {
            acc[0][pc] = MFMA(a0.v, bf[pc].v, acc[0][pc]);
            acc[1][pc] = MFMA(a1.v, bf[pc].v, acc[1][pc]);
        }
    };

    loadf(0); commit(0); __syncthreads();
#pragma unroll
    for (int c = 0; c < 6; ++c) {
        if (c < 5) loadf(c + 1);             // prefetch (in flight during MFMAs)
        compute(c, c & 1);
        if (c < 5) { commit((c + 1) & 1); __syncthreads(); }
    }
    __syncthreads();                         // tile dead -> alias as red

    // wave partials -> red[m][pl][wv], cross-wave reduce
#pragma unroll
    for (int mh = 0; mh < 2; ++mh)
#pragma unroll
        for (int pc = 0; pc < 4; ++pc)
#pragma unroll
            for (int r = 0; r < 4; ++r)
                red[((mh * 16 + q * 4 + r) * 64 + pc * 16 + ln) * 4 + wv] = acc[mh][pc][r];
    __syncthreads();

    // epilogue: thread t -> m = t>>3, 8 p-cols from (t&7)*8
    const int m = t >> 3, pl0 = (t & 7) << 3;
    const float bias = att_b[m];
    Frag hw;
#pragma unroll
    for (int g = 0; g < 2; ++g) {
        f32x4_t v;
#pragma unroll
        for (int j = 0; j < 4; ++j) {
            const int pl = pl0 + g * 4 + j;
            f32x4_t r4 = *(const f32x4_t*)&red[(m * 64 + pl) * 4];
            float x = r4[0] + r4[1] + r4[2] + r4[3] + bias;
            x = x > 0.f ? x : 0.f;
            v[j] = x;
            hw.s[g * 4 + j] = (p0 + pl < 676) ? f2b(x) : (u16)0;
        }
        const int p = p0 + pl0 + g * 4;
        if (p + 3 < 676) {
            *(f32x4_t*)(att_out + (size_t)(b * 32 + m) * 676 + p) = v;
        } else {
#pragma unroll
            for (int j = 0; j < 4; ++j)
                if (p + j < 676) att_out[(size_t)(b * 32 + m) * 676 + p + j] = v[j];
        }
    }
    *(uint32x4*)(att_pad + (size_t)(b * 32 + m) * 704 + p0 + pl0) = hw.u4;
}

// ---- Pass 2: pooled[b] = att[b](32x704) @ fm[b]^T / 676 ----
// grid (24, 64). Tile 32m x 32c; 22 k-steps striped over 4 waves, no barriers
// in loop. B from f32 fm (L3-hot) with inline cvt; A = att_pad bf16 dwordx4.
// Fuses Sum|pooled| -> p_sums[b] (one atomicAdd per block).
__global__ __launch_bounds__(256) void k_pool(
    const float* __restrict__ fm, const u16* __restrict__ att_pad,
    float* __restrict__ pooled, float* __restrict__ p_sums)
{
    const int b  = blockIdx.y;
    const int n0 = blockIdx.x << 5;
    const int t  = threadIdx.x;
    const int wv = t >> 6, l = t & 63, q = l >> 4, ln = l & 15;

    __shared__ float red[32][32][4];
    __shared__ float rs[4];

    const u16*   Ab = att_pad + (size_t)b * 32 * 704;
    const float* B0 = fm + (size_t)(b * 768 + n0 + ln) * 676;
    const float* B1 = fm + (size_t)(b * 768 + n0 + 16 + ln) * 676;

    f32x4_t acc[2][2] = {{{0.f,0.f,0.f,0.f},{0.f,0.f,0.f,0.f}},
                         {{0.f,0.f,0.f,0.f},{0.f,0.f,0.f,0.f}}};

    for (int it = wv; it < 22; it += 4) {
        const int k = it * 32 + q * 8;
        Frag a0, a1, b0, b1;
        a0.u4 = *(const uint32x4*)(Ab + (size_t)ln * 704 + k);
        a1.u4 = *(const uint32x4*)(Ab + (size_t)(16 + ln) * 704 + k);
        if (it < 21) {
            load8_cvt(B0 + k, b0);
            load8_cvt(B1 + k, b1);
        } else {
            // k0=672: only 672..675 valid; att_pad cols >=676 are zero.
            // One in-bounds float4 (q==0), zeros elsewhere — never read past fm.
            b0.u[0]=0u; b0.u[1]=0u; b0.u[2]=0u; b0.u[3]=0u;
            b1.u[0]=0u; b1.u[1]=0u; b1.u[2]=0u; b1.u[3]=0u;
            if (q == 0) {
                f32x4_t x0 = *(const f32x4_t*)(B0 + 672);
                f32x4_t x1 = *(const f32x4_t*)(B1 + 672);
#pragma unroll
                for (int j = 0; j < 4; ++j) { b0.s[j] = f2b(x0[j]); b1.s[j] = f2b(x1[j]); }
            }
        }
        acc[0][0] = MFMA(a0.v, b0.v, acc[0][0]);
        acc[0][1] = MFMA(a0.v, b1.v, acc[0][1]);
        acc[1][0] = MFMA(a1.v, b0.v, acc[1][0]);
        acc[1][1] = MFMA(a1.v, b1.v, acc[1][1]);
    }

#pragma unroll
    for (int mh = 0; mh < 2; ++mh)
#pragma unroll
        for (int ch = 0; ch < 2; ++ch)
#pragma unroll
            for (int r = 0; r < 4; ++r)
                red[mh * 16 + q * 4 + r][ch * 16 + ln][wv] = acc[mh][ch][r];
    __syncthreads();

    const float sc = 1.0f / 676.0f;
    const int m = t >> 3, c0 = (t & 7) << 2;
    float ls = 0.f;
#pragma unroll
    for (int j = 0; j < 4; ++j) {
        const int cl = c0 + j;
        f32x4_t v4 = *(const f32x4_t*)&red[m][cl][0];
        float v = (v4[0] + v4[1] + v4[2] + v4[3]) * sc;
        pooled[(size_t)(b * 32 + m) * 768 + n0 + cl] = v;
        ls += fabsf(v);
    }
    for (int off = 32; off > 0; off >>= 1) ls += __shfl_down(ls, off);
    if (l == 0) rs[wv] = ls;
    __syncthreads();
    if (t == 0) atomicAdd(p_sums + b, rs[0] + rs[1] + rs[2] + rs[3]);
}

// ---- Pass 3 (apply only): signed sqrt + L2 normalize ----
__global__ __launch_bounds__(256) void k_norm(
    const float* __restrict__ pooled, const float* __restrict__ p_sums,
    float* __restrict__ fm_out, u16* __restrict__ fmn16)
{
    const int b = blockIdx.x;
    const size_t base = (size_t)b * 24576 + (size_t)blockIdx.y * 2048;
    const float tot = p_sums[b] + 24576.f * 1e-12f;
    const float inv = 1.f / fmaxf(sqrtf(tot), 1e-12f);
    const int t = threadIdx.x;
#pragma unroll
    for (int i = 0; i < 8; ++i) {
        const size_t idx = base + i * 256 + t;
        float x = pooled[idx];
        float v = (x == 0.f) ? 0.f : copysignf(sqrtf(fabsf(x) + 1e-12f), x);
        float o = v * inv;
        fm_out[idx] = o;
        fmn16[idx]  = f2b(o);
    }
}

// ---- Pass 4: p partials, K=24576 split into 48 slabs of 512 ----
__global__ __launch_bounds__(256) void k_fc(
    const u16* __restrict__ fmn16, const float* __restrict__ fc_w,
    float* __restrict__ p_part)
{
    const int ntile = blockIdx.x;          // 0..12
    const int slab  = blockIdx.y;          // 0..47
    const int t = threadIdx.x;
    const int wv = t >> 6, l = t & 63, q = l >> 4, ln = l & 15;
    const int n = ntile * 16 + ln;
    const int kbase = slab * 512;

    const u16*   Ab = fmn16 + (size_t)(wv * 16 + ln) * 24576 + kbase + q * 8;
    const float* Bb = fc_w + (size_t)n * 24576 + kbase + q * 8;
    const bool nok = n < 200;

    f32x4_t acc = {0.f, 0.f, 0.f, 0.f};
#pragma unroll
    for (int kk = 0; kk < 512; kk += 32) {
        Frag af, bf2;
        af.u4 = *(const uint32x4*)(Ab + kk);
        if (nok) load8_cvt(Bb + kk, bf2);
        else { bf2.u[0] = 0u; bf2.u[1] = 0u; bf2.u[2] = 0u; bf2.u[3] = 0u; }
        acc = MFMA(af.v, bf2.v, acc);
    }
#pragma unroll
    for (int r = 0; r < 4; ++r) {
        const int bb = wv * 16 + q * 4 + r;
        p_part[(size_t)(slab * 64 + bb) * 208 + ntile * 16 + ln] = acc[r];
    }
}

// ---- Pass 5: reduce 48 slabs, scale 100, + bias ----
__global__ __launch_bounds__(256) void k_fin(
    const float* __restrict__ p_part, const float* __restrict__ fc_b,
    float* __restrict__ p_out)
{
    const int tid = blockIdx.x * 256 + threadIdx.x;   // 50*256 == 12800
    const int b = tid / 200, n = tid - b * 200;
    float s = 0.f;
#pragma unroll
    for (int sl = 0; sl < 48; ++sl) s += p_part[(size_t)(sl * 64 + b) * 208 + n];
    p_out[tid] = s * 100.f + fc_b[n];
}

extern "C" void kernel_launch(void* const* d_in, const int* in_sizes, int n_in,
                              void* d_out, int out_size, void* d_ws, size_t ws_size,
                              hipStream_t stream)
{
    const float* fm    = (const float*)d_in[0];
    const float* att_w = (const float*)d_in[1];
    const float* att_b = (const float*)d_in[2];
    const float* fc_w  = (const float*)d_in[3];
    const float* fc_b  = (const float*)d_in[4];

    float* out     = (float*)d_out;
    float* p_out   = out;                         // [64][200]
    float* fm_out  = out + 12800;                 // [64][32][768]
    float* att_out = out + 12800 + 64 * 32 * 768; // [64][32][676]

    char* ws = (char*)d_ws;
    // att_pad (2,883,584 B) and p_part (2,555,904 B): disjoint lifetimes -> overlay.
    u16*   att_pad = (u16*)ws;
    float* p_part  = (float*)ws;
    float* pooled  = (float*)(ws + 2883584);              // 6,291,456 B
    u16*   fmn16   = (u16*)(ws + 2883584 + 6291456);      // 3,145,728 B
    float* p_sums  = (float*)(ws + 2883584 + 6291456 + 3145728); // 256 B

    k_att <<<dim3(11, 64), 256, 0, stream>>>(fm, att_w, att_b, att_out, att_pad, p_sums);
    k_pool<<<dim3(24, 64), 256, 0, stream>>>(fm, att_pad, pooled, p_sums);
    k_norm<<<dim3(64, 12), 256, 0, stream>>>(pooled, p_sums, fm_out, fmn16);
    k_fc  <<<dim3(13, 48), 256, 0, stream>>>(fmn16, fc_w, p_part);
    k_fin <<<dim3(50),     256, 0, stream>>>(p_part, fc_b, p_out);
}